// Round 1
// baseline (810.030 us; speedup 1.0000x reference)
//
#include <hip/hip_runtime.h>
#include <math.h>

#define HID   128
#define MAXN  100000
#define MAXE  300000
#define EVT   4096
#define NNODE 20000
#define NEDGE 320000

// ---------------- workspace layout (bytes) ----------------
// EVENT arena
#define OFF_REP_SRC   0u
#define OFF_REP_DST   400128u
#define OFF_CNT_SRC   800256u
#define OFF_CNT_DST   1200384u
#define OFF_SUM_SRC   1600512u      // 4096*640 f32
#define OFF_SUM_DST   12086272u     // 4096*640 f32
#define OFF_XG        22572032u     // 8192*640 f32
#define OFF_HG        43543552u     // 8192*128 f32
#define OFF_GI        47737856u     // 8192*384 f32
#define OFF_GH        60320768u     // 8192*384 f32
#define OFF_NEWMEM    72903680u     // 8192*128 f32
// NODE arena (time-aliased onto event arena; all event consumers finish first)
#define OFF_X         0u            // 20000*128 f32
#define OFF_QKVSE     10240000u     // 20000*768 f32 : q|k|v|skip|qe(256)
#define OFF_WALL      71680000u     // 768*128 f32
#define OFF_BALL      72073216u     // 768 f32
#define OFF_ALPHA     72077312u     // 320000 f32
#define OFF_DEG       73357312u     // 20000 i32
#define OFF_OFFS      73437440u     // 20001 i32
#define OFF_CURSOR    73517568u     // 20000 i32
#define OFF_SORTED    73597696u     // 320000 i32
#define OFF_SACC      74877696u     // 20000*256 f32
// peak: 95,357,696 bytes (~91 MB)

__device__ __forceinline__ float sigmoidf_(float x) { return 1.f / (1.f + __expf(-x)); }

// ---- rep/count tables for scatter-mean ----
__global__ void k_tables(const int* __restrict__ src_ids, const int* __restrict__ dst_ids,
                         unsigned* rep_src, unsigned* rep_dst, int* cnt_src, int* cnt_dst) {
    int i = blockIdx.x * blockDim.x + threadIdx.x;
    if (i >= EVT) return;
    int s = src_ids[i], d = dst_ids[i];
    atomicMin(&rep_src[s], (unsigned)i);
    atomicAdd(&cnt_src[s], 1);
    atomicMin(&rep_dst[d], (unsigned)i);
    atomicAdd(&cnt_dst[d], 1);
}

// ---- build messages and atomically aggregate into per-rep sums ----
__global__ void k_message(const int* __restrict__ et_ids, const int* __restrict__ src_ids,
                          const float* __restrict__ src_mask, const int* __restrict__ dst_ids,
                          const float* __restrict__ dst_mask, const int* __restrict__ ev_eids,
                          const float* __restrict__ ev_emb, const float* __restrict__ ev_mask,
                          const float* __restrict__ ev_ts, const float* __restrict__ memory,
                          const float* __restrict__ last_update, const float* __restrict__ time_w,
                          const float* __restrict__ time_b, const unsigned* __restrict__ rep_src,
                          const unsigned* __restrict__ rep_dst, float* sum_src, float* sum_dst) {
    int i = blockIdx.x;
    int c = threadIdx.x;
    int et = et_ids[i];
    float sm = src_mask[i], dm = dst_mask[i], em = ev_mask[i], ts = ev_ts[i];
    int sid = src_ids[i], did = dst_ids[i], eid = ev_eids[i];
    float isnode = (et == 3 || et == 4) ? 1.f : 0.f;
    float rel = ts - last_update[eid] * dm;
    float tval = ts * isnode + rel * dm;
    float tse = __cosf(tval * time_w[c] + time_b[c]) * em;   // ts_emb already * event_mask
    float typ = (float)et;
    float sv = memory[(size_t)sid * HID + c] * sm;
    float dv = memory[(size_t)did * HID + c] * dm;
    float ev = ev_emb[(size_t)i * HID + c];
    float* ps = sum_src + (size_t)rep_src[sid] * 640;
    atomicAdd(ps + c,         typ * em);
    atomicAdd(ps + 128 + c,   sv * em);
    atomicAdd(ps + 256 + c,   dv * em);
    atomicAdd(ps + 384 + c,   tse * em);
    atomicAdd(ps + 512 + c,   ev * em);
    float* pd = sum_dst + (size_t)rep_dst[did] * 640;
    atomicAdd(pd + c,         typ * dm);
    atomicAdd(pd + 128 + c,   dv * dm);
    atomicAdd(pd + 256 + c,   sv * dm);
    atomicAdd(pd + 384 + c,   tse * dm);
    atomicAdd(pd + 512 + c,   ev * dm);
}

// ---- gather aggregated means back per event into Xg (8192 x 640) ----
__global__ void k_build_xg(const int* __restrict__ src_ids, const int* __restrict__ dst_ids,
                           const unsigned* __restrict__ rep_src, const unsigned* __restrict__ rep_dst,
                           const int* __restrict__ cnt_src, const int* __restrict__ cnt_dst,
                           const float* __restrict__ sum_src, const float* __restrict__ sum_dst,
                           float* __restrict__ Xg) {
    int r = blockIdx.x;
    int c = blockIdx.y * 128 + threadIdx.x;  // gridDim.y = 5
    float v;
    if (r < EVT) {
        int id = src_ids[r];
        int cnt = cnt_src[id]; if (cnt < 1) cnt = 1;
        v = sum_src[(size_t)rep_src[id] * 640 + c] / (float)cnt;
    } else {
        int id = dst_ids[r - EVT];
        int cnt = cnt_dst[id]; if (cnt < 1) cnt = 1;
        v = sum_dst[(size_t)rep_dst[id] * 640 + c] / (float)cnt;
    }
    Xg[(size_t)r * 640 + c] = v;
}

__global__ void k_build_hg(const int* __restrict__ src_ids, const int* __restrict__ dst_ids,
                           const float* __restrict__ memory, float* __restrict__ Hg) {
    int r = blockIdx.x, c = threadIdx.x;
    int id = (r < EVT) ? src_ids[r] : dst_ids[r - EVT];
    Hg[(size_t)r * HID + c] = memory[(size_t)id * HID + c];
}

// ---- generic fp32 tiled GEMM: C[M,N] (+)= A[M,K] @ W[N,K]^T (+ bias) ----
// BM=64, BN=128, BK=16, 256 threads, 4x8 microtile. N must be multiple of 128, K multiple of 16.
__global__ __launch_bounds__(256) void k_gemm(const float* __restrict__ A,
                                              const float* __restrict__ W,
                                              const float* __restrict__ bias,
                                              float* __restrict__ C,
                                              int M, int N, int K, int acc) {
    __shared__ float As[16][68];
    __shared__ float Ws[16][132];
    int tid = threadIdx.x;
    int bm = blockIdx.x * 64;
    int bn = blockIdx.y * 128;
    int tx = tid & 15, ty = tid >> 4;
    float accr[4][8];
#pragma unroll
    for (int i = 0; i < 4; i++)
#pragma unroll
        for (int j = 0; j < 8; j++) accr[i][j] = 0.f;
    int ar = tid >> 2, ak = (tid & 3) * 4;   // A tile loader: 64 rows x 16 k
    int wr = tid >> 1, wk = (tid & 1) * 8;   // W tile loader: 128 rows x 16 k
    for (int k0 = 0; k0 < K; k0 += 16) {
        float4 av = make_float4(0.f, 0.f, 0.f, 0.f);
        int arow = bm + ar;
        if (arow < M) av = *(const float4*)(A + (size_t)arow * K + k0 + ak);
        As[ak + 0][ar] = av.x; As[ak + 1][ar] = av.y; As[ak + 2][ar] = av.z; As[ak + 3][ar] = av.w;
        int wrow = bn + wr;
        float4 w0 = *(const float4*)(W + (size_t)wrow * K + k0 + wk);
        float4 w1 = *(const float4*)(W + (size_t)wrow * K + k0 + wk + 4);
        Ws[wk + 0][wr] = w0.x; Ws[wk + 1][wr] = w0.y; Ws[wk + 2][wr] = w0.z; Ws[wk + 3][wr] = w0.w;
        Ws[wk + 4][wr] = w1.x; Ws[wk + 5][wr] = w1.y; Ws[wk + 6][wr] = w1.z; Ws[wk + 7][wr] = w1.w;
        __syncthreads();
#pragma unroll
        for (int kk = 0; kk < 16; ++kk) {
            float a[4], b[8];
#pragma unroll
            for (int i = 0; i < 4; i++) a[i] = As[kk][ty * 4 + i];
#pragma unroll
            for (int j = 0; j < 8; j++) b[j] = Ws[kk][tx * 8 + j];
#pragma unroll
            for (int i = 0; i < 4; i++)
#pragma unroll
                for (int j = 0; j < 8; j++) accr[i][j] += a[i] * b[j];
        }
        __syncthreads();
    }
#pragma unroll
    for (int i = 0; i < 4; i++) {
        int row = bm + ty * 4 + i;
        if (row >= M) continue;
#pragma unroll
        for (int j = 0; j < 8; j++) {
            int col = bn + tx * 8 + j;
            float v = accr[i][j];
            if (bias) v += bias[col];
            if (acc) v += C[(size_t)row * N + col];
            C[(size_t)row * N + col] = v;
        }
    }
}

// ---- GRU gate combine ----
__global__ void k_gru(const float* __restrict__ Gi, const float* __restrict__ Gh,
                      const float* __restrict__ Hg, float* __restrict__ newmem) {
    int r = blockIdx.x, c = threadIdx.x;
    const float* gi = Gi + (size_t)r * 384;
    const float* gh = Gh + (size_t)r * 384;
    float rg = sigmoidf_(gi[c] + gh[c]);
    float z  = sigmoidf_(gi[128 + c] + gh[128 + c]);
    float n  = tanhf(gi[256 + c] + rg * gh[256 + c]);
    float h  = Hg[(size_t)r * HID + c];
    newmem[(size_t)r * HID + c] = (1.f - z) * n + z * h;
}

// in-place memory scatter (duplicates write bitwise-identical values; benign)
__global__ void k_scatter(float* __restrict__ memory, const int* __restrict__ ids,
                          const float* __restrict__ newmem) {
    int i = blockIdx.x, c = threadIdx.x;
    memory[(size_t)ids[i] * HID + c] = newmem[(size_t)i * HID + c];
}

// ---- fused node-GEMM weight: rows q|k|v|skip|qe  (qe rows: wq^T·we fold) ----
__global__ void k_wall(const float* __restrict__ wq, const float* __restrict__ wk_,
                       const float* __restrict__ wv, const float* __restrict__ wskip,
                       const float* __restrict__ we, const float* __restrict__ bq,
                       const float* __restrict__ bk, const float* __restrict__ bv,
                       const float* __restrict__ bskip, float* __restrict__ Wall,
                       float* __restrict__ ball) {
    int row = blockIdx.x;   // 0..767
    int k = threadIdx.x;    // 0..127
    float v;
    if (row < 128)      v = wq[row * 128 + k];
    else if (row < 256) v = wk_[(row - 128) * 128 + k];
    else if (row < 384) v = wv[(row - 256) * 128 + k];
    else if (row < 512) v = wskip[(row - 384) * 128 + k];
    else {
        int j = row - 512;
        float a = 0.f;
        for (int t = 0; t < 128; t++) a += wq[t * 128 + k] * we[t * 256 + j];
        v = a;
    }
    Wall[row * 128 + k] = v;
    if (k == 0) {
        float b;
        if (row < 128)      b = bq[row];
        else if (row < 256) b = bk[row - 128];
        else if (row < 384) b = bv[row - 256];
        else if (row < 512) b = bskip[row - 384];
        else { int j = row - 512; float a = 0.f; for (int t = 0; t < 128; t++) a += bq[t] * we[t * 256 + j]; b = a; }
        ball[row] = b;
    }
}

__global__ void k_x(const int* __restrict__ node_ids, const float* __restrict__ nf,
                    const float* __restrict__ memory, float* __restrict__ X) {
    int p = blockIdx.x, c = threadIdx.x;
    int nid = node_ids[p];
    X[(size_t)p * HID + c] = nf[(size_t)nid * HID + c] + memory[(size_t)nid * HID + c];
}

// ---- per-edge attention logits (wave per edge) + dst-degree histogram ----
__global__ __launch_bounds__(256) void k_alpha(const float* __restrict__ QK,
        const int* __restrict__ eidx, const int* __restrict__ edge_ids,
        const float* __restrict__ last_update, const float* __restrict__ time_w,
        const float* __restrict__ time_b, const float* __restrict__ ef,
        const int* __restrict__ tptr, float* __restrict__ alpha, int* __restrict__ deg) {
    int wave = threadIdx.x >> 6, lane = threadIdx.x & 63;
    int j = blockIdx.x * 4 + wave;                // NEDGE/4 blocks, exact
    int s = eidx[j], d = eidx[NEDGE + j];
    int eid = edge_ids[j];
    float rt = (float)(*tptr) - last_update[eid];
    const float* qd  = QK + (size_t)d * 768;
    const float* ks  = QK + (size_t)s * 768 + 128;
    const float* qet = QK + (size_t)d * 768 + 512;
    const float* qef = QK + (size_t)d * 768 + 640;
    float p = 0.f;
#pragma unroll
    for (int u = 0; u < 2; ++u) {
        int c = lane + u * 64;
        float cv = __cosf(rt * time_w[c] + time_b[c]);
        p += qd[c] * ks[c] + qet[c] * cv + qef[c] * ef[(size_t)eid * HID + c];
    }
#pragma unroll
    for (int m = 32; m > 0; m >>= 1) p += __shfl_xor(p, m, 64);
    if (lane == 0) {
        alpha[j] = p * 0.08838834764831845f;      // 1/sqrt(128)
        atomicAdd(&deg[d], 1);
    }
}

// ---- exclusive prefix sum over 20000 degrees (single block) ----
__global__ __launch_bounds__(1024) void k_scan(const int* __restrict__ deg,
                                               int* __restrict__ offs, int* __restrict__ cursor) {
    __shared__ int part[1024];
    int t = threadIdx.x;
    int base = t * 20;
    int loc[20]; int s = 0;
    for (int i = 0; i < 20; i++) { int idx = base + i; int v = (idx < NNODE) ? deg[idx] : 0; loc[i] = s; s += v; }
    part[t] = s; __syncthreads();
    for (int dgap = 1; dgap < 1024; dgap <<= 1) {
        int v = (t >= dgap) ? part[t - dgap] : 0;
        __syncthreads();
        part[t] += v;
        __syncthreads();
    }
    int excl = (t == 0) ? 0 : part[t - 1];
    for (int i = 0; i < 20; i++) { int idx = base + i; if (idx < NNODE) { int o = excl + loc[i]; offs[idx] = o; cursor[idx] = o; } }
    if (t == 1023) offs[NNODE] = part[1023];
}

__global__ void k_sortscat(const int* __restrict__ eidx, int* __restrict__ cursor,
                           int* __restrict__ sorted) {
    int j = blockIdx.x * blockDim.x + threadIdx.x;
    if (j >= NEDGE) return;
    int d = eidx[NEDGE + j];
    int pos = atomicAdd(&cursor[d], 1);
    sorted[pos] = j;
}

// ---- per-node softmax + weighted accumulation (block per node, no atomics) ----
__global__ __launch_bounds__(128) void k_node(const float* __restrict__ QK,
        const int* __restrict__ offs, const int* __restrict__ sorted,
        const float* __restrict__ alpha, const int* __restrict__ eidx,
        const int* __restrict__ edge_ids, const float* __restrict__ last_update,
        const float* __restrict__ time_w, const float* __restrict__ time_b,
        const float* __restrict__ ef, const int* __restrict__ tptr,
        float* __restrict__ out, float* __restrict__ sacc) {
    __shared__ int   sj[256];
    __shared__ float sal[256];
    int n = blockIdx.x, c = threadIdx.x;
    int start = offs[n], end = offs[n + 1];
    int deg = end - start;
    float skipv = QK[(size_t)n * 768 + 384 + c];
    if (deg == 0) {
        out[(size_t)n * HID + c] = skipv;
        sacc[(size_t)n * 256 + c] = 0.f;
        sacc[(size_t)n * 256 + 128 + c] = 0.f;
        return;
    }
    bool use_lds = (deg <= 256);
    if (use_lds) {
        for (int e = c; e < deg; e += 128) { int j = sorted[start + e]; sj[e] = j; sal[e] = alpha[j]; }
        __syncthreads();
    }
    float amax = -1e30f;
    for (int e = 0; e < deg; ++e) amax = fmaxf(amax, use_lds ? sal[e] : alpha[sorted[start + e]]);
    float denom = 0.f;
    for (int e = 0; e < deg; ++e) denom += __expf((use_lds ? sal[e] : alpha[sorted[start + e]]) - amax);
    float inv = 1.f / fmaxf(denom, 1e-16f);
    float tw = time_w[c], tb = time_b[c];
    float tf = (float)(*tptr);
    float va = 0.f, s0 = 0.f, s1 = 0.f;
    for (int e = 0; e < deg; ++e) {
        int j = use_lds ? sj[e] : sorted[start + e];
        float al = use_lds ? sal[e] : alpha[j];
        float p = __expf(al - amax) * inv;
        int s = eidx[j];
        int eid = edge_ids[j];
        float rt = tf - last_update[eid];
        va += p * QK[(size_t)s * 768 + 256 + c];           // v[src]
        s0 += p * __cosf(rt * tw + tb);                    // time-embed half of attr
        s1 += p * ef[(size_t)eid * HID + c];               // edge-feature half
    }
    out[(size_t)n * HID + c] = va + skipv;
    sacc[(size_t)n * 256 + c] = s0;
    sacc[(size_t)n * 256 + 128 + c] = s1;
}

extern "C" void kernel_launch(void* const* d_in, const int* in_sizes, int n_in,
                              void* d_out, int out_size, void* d_ws, size_t ws_size,
                              hipStream_t stream) {
    const int*   et_ids        = (const int*)d_in[0];
    const int*   src_ids       = (const int*)d_in[1];
    const float* src_mask      = (const float*)d_in[2];
    const int*   dst_ids       = (const int*)d_in[3];
    const float* dst_mask      = (const float*)d_in[4];
    const int*   ev_eids       = (const int*)d_in[5];
    const float* ev_emb        = (const float*)d_in[6];
    const float* ev_mask       = (const float*)d_in[7];
    const float* ev_ts         = (const float*)d_in[8];
    const int*   node_ids      = (const int*)d_in[9];
    const int*   edge_ids      = (const int*)d_in[10];
    const int*   edge_index    = (const int*)d_in[11];
    const int*   tptr          = (const int*)d_in[12];
    float*       memory        = (float*)d_in[13];        // mutated in place (restored by harness)
    const float* last_update   = (const float*)d_in[14];
    const float* node_features = (const float*)d_in[15];
    const float* edge_features = (const float*)d_in[16];
    const float* time_w        = (const float*)d_in[17];
    const float* time_b        = (const float*)d_in[18];
    const float* w_ih          = (const float*)d_in[19];
    const float* w_hh          = (const float*)d_in[20];
    const float* b_ih          = (const float*)d_in[21];
    const float* b_hh          = (const float*)d_in[22];
    const float* wq            = (const float*)d_in[23];
    const float* bq            = (const float*)d_in[24];
    const float* wk            = (const float*)d_in[25];
    const float* bk            = (const float*)d_in[26];
    const float* wv            = (const float*)d_in[27];
    const float* bv            = (const float*)d_in[28];
    const float* we            = (const float*)d_in[29];
    const float* wskip         = (const float*)d_in[30];
    const float* bskip         = (const float*)d_in[31];
    float* out = (float*)d_out;
    char*  wsb = (char*)d_ws;

    unsigned* rep_src = (unsigned*)(wsb + OFF_REP_SRC);
    unsigned* rep_dst = (unsigned*)(wsb + OFF_REP_DST);
    int*   cnt_src = (int*)(wsb + OFF_CNT_SRC);
    int*   cnt_dst = (int*)(wsb + OFF_CNT_DST);
    float* sum_src = (float*)(wsb + OFF_SUM_SRC);
    float* sum_dst = (float*)(wsb + OFF_SUM_DST);
    float* Xg      = (float*)(wsb + OFF_XG);
    float* Hg      = (float*)(wsb + OFF_HG);
    float* Gi      = (float*)(wsb + OFF_GI);
    float* Gh      = (float*)(wsb + OFF_GH);
    float* newmem  = (float*)(wsb + OFF_NEWMEM);
    float* X       = (float*)(wsb + OFF_X);
    float* QKVSE   = (float*)(wsb + OFF_QKVSE);
    float* Wall    = (float*)(wsb + OFF_WALL);
    float* ball    = (float*)(wsb + OFF_BALL);
    float* alpha   = (float*)(wsb + OFF_ALPHA);
    int*   deg     = (int*)(wsb + OFF_DEG);
    int*   offs    = (int*)(wsb + OFF_OFFS);
    int*   cursor  = (int*)(wsb + OFF_CURSOR);
    int*   sorted  = (int*)(wsb + OFF_SORTED);
    float* sacc    = (float*)(wsb + OFF_SACC);

    // ---- event phase ----
    hipMemsetAsync(wsb + OFF_REP_SRC, 0xFF, 800256, stream);
    hipMemsetAsync(wsb + OFF_CNT_SRC, 0, 800256, stream);
    hipMemsetAsync(wsb + OFF_SUM_SRC, 0, 2u * 10485760u, stream);
    k_tables<<<16, 256, 0, stream>>>(src_ids, dst_ids, rep_src, rep_dst, cnt_src, cnt_dst);
    k_message<<<EVT, 128, 0, stream>>>(et_ids, src_ids, src_mask, dst_ids, dst_mask, ev_eids,
                                       ev_emb, ev_mask, ev_ts, memory, last_update, time_w, time_b,
                                       rep_src, rep_dst, sum_src, sum_dst);
    k_build_xg<<<dim3(2 * EVT, 5), 128, 0, stream>>>(src_ids, dst_ids, rep_src, rep_dst,
                                                     cnt_src, cnt_dst, sum_src, sum_dst, Xg);
    k_build_hg<<<2 * EVT, 128, 0, stream>>>(src_ids, dst_ids, memory, Hg);
    k_gemm<<<dim3(128, 3), 256, 0, stream>>>(Xg, w_ih, b_ih, Gi, 2 * EVT, 384, 640, 0);
    k_gemm<<<dim3(128, 3), 256, 0, stream>>>(Hg, w_hh, b_hh, Gh, 2 * EVT, 384, 128, 0);
    k_gru<<<2 * EVT, 128, 0, stream>>>(Gi, Gh, Hg, newmem);
    k_scatter<<<EVT, 128, 0, stream>>>(memory, src_ids, newmem);                       // src first
    k_scatter<<<EVT, 128, 0, stream>>>(memory, dst_ids, newmem + (size_t)EVT * HID);   // dst overrides

    // ---- node phase ----
    k_wall<<<768, 128, 0, stream>>>(wq, wk, wv, wskip, we, bq, bk, bv, bskip, Wall, ball);
    k_x<<<NNODE, 128, 0, stream>>>(node_ids, node_features, memory, X);
    k_gemm<<<dim3(313, 6), 256, 0, stream>>>(X, Wall, ball, QKVSE, NNODE, 768, 128, 0);
    hipMemsetAsync(wsb + OFF_DEG, 0, 80128, stream);
    k_alpha<<<NEDGE / 4, 256, 0, stream>>>(QKVSE, edge_index, edge_ids, last_update,
                                           time_w, time_b, edge_features, tptr, alpha, deg);
    k_scan<<<1, 1024, 0, stream>>>(deg, offs, cursor);
    k_sortscat<<<1250, 256, 0, stream>>>(edge_index, cursor, sorted);
    k_node<<<NNODE, 128, 0, stream>>>(QKVSE, offs, sorted, alpha, edge_index, edge_ids,
                                      last_update, time_w, time_b, edge_features, tptr, out, sacc);
    k_gemm<<<dim3(313, 1), 256, 0, stream>>>(sacc, we, nullptr, out, NNODE, 128, 256, 1);
}

// Round 2
// 723.757 us; speedup vs baseline: 1.1192x; 1.1192x over previous
//
#include <hip/hip_runtime.h>
#include <math.h>

#define HID   128
#define MAXN  100000
#define MAXE  300000
#define EVT   4096
#define NNODE 20000
#define NEDGE 320000

// ---------------- workspace layout (bytes) ----------------
// EVENT arena
#define OFF_REP_SRC   0u
#define OFF_REP_DST   400128u
#define OFF_CNT_SRC   800256u
#define OFF_CNT_DST   1200384u
#define OFF_SUM_SRC   1600512u      // 4096*640 f32
#define OFF_SUM_DST   12086272u     // 4096*640 f32
#define OFF_XG        22572032u     // 8192*640 f32
#define OFF_HG        43543552u     // 8192*128 f32
#define OFF_GI        47737856u     // 8192*384 f32
#define OFF_GH        60320768u     // 8192*384 f32
#define OFF_NEWMEM    72903680u     // 8192*128 f32
// NODE arena (time-aliased onto event arena; all event consumers finish first)
#define OFF_X         0u            // 20000*128 f32
#define OFF_QKVSE     10240000u     // 20000*768 f32 : q|k|v|skip|qe(256)
#define OFF_WALL      71680000u     // 768*128 f32
#define OFF_BALL      72073216u     // 768 f32
#define OFF_DEG       73357312u     // 20000 i32
#define OFF_OFFS      73437440u     // 20001 i32
#define OFF_CURSOR    73517568u     // 20000 i32
#define OFF_SORTED    73597696u     // 320000 i32
#define OFF_SACC      74877696u     // 20000*256 f32
// peak: 95,357,696 bytes (~91 MB)

__device__ __forceinline__ float sigmoidf_(float x) { return 1.f / (1.f + __expf(-x)); }

// ---- rep/count tables for scatter-mean ----
__global__ void k_tables(const int* __restrict__ src_ids, const int* __restrict__ dst_ids,
                         unsigned* rep_src, unsigned* rep_dst, int* cnt_src, int* cnt_dst) {
    int i = blockIdx.x * blockDim.x + threadIdx.x;
    if (i >= EVT) return;
    int s = src_ids[i], d = dst_ids[i];
    atomicMin(&rep_src[s], (unsigned)i);
    atomicAdd(&cnt_src[s], 1);
    atomicMin(&rep_dst[d], (unsigned)i);
    atomicAdd(&cnt_dst[d], 1);
}

// ---- build messages and aggregate into per-rep sums (fast path when unique) ----
__global__ void k_message(const int* __restrict__ et_ids, const int* __restrict__ src_ids,
                          const float* __restrict__ src_mask, const int* __restrict__ dst_ids,
                          const float* __restrict__ dst_mask, const int* __restrict__ ev_eids,
                          const float* __restrict__ ev_emb, const float* __restrict__ ev_mask,
                          const float* __restrict__ ev_ts, const float* __restrict__ memory,
                          const float* __restrict__ last_update, const float* __restrict__ time_w,
                          const float* __restrict__ time_b, const unsigned* __restrict__ rep_src,
                          const unsigned* __restrict__ rep_dst, const int* __restrict__ cnt_src,
                          const int* __restrict__ cnt_dst, float* sum_src, float* sum_dst) {
    int i = blockIdx.x;
    int c = threadIdx.x;
    int et = et_ids[i];
    float sm = src_mask[i], dm = dst_mask[i], em = ev_mask[i], ts = ev_ts[i];
    int sid = src_ids[i], did = dst_ids[i], eid = ev_eids[i];
    float isnode = (et == 3 || et == 4) ? 1.f : 0.f;
    float rel = ts - last_update[eid] * dm;
    float tval = ts * isnode + rel * dm;
    float tse = __cosf(tval * time_w[c] + time_b[c]) * em;
    float typ = (float)et;
    float sv = memory[(size_t)sid * HID + c] * sm;
    float dv = memory[(size_t)did * HID + c] * dm;
    float ev = ev_emb[(size_t)i * HID + c];
    float* ps = sum_src + (size_t)rep_src[sid] * 640;
    if (cnt_src[sid] == 1) {
        ps[c] = typ * em; ps[128 + c] = sv * em; ps[256 + c] = dv * em;
        ps[384 + c] = tse * em; ps[512 + c] = ev * em;
    } else {
        atomicAdd(ps + c, typ * em);
        atomicAdd(ps + 128 + c, sv * em);
        atomicAdd(ps + 256 + c, dv * em);
        atomicAdd(ps + 384 + c, tse * em);
        atomicAdd(ps + 512 + c, ev * em);
    }
    float* pd = sum_dst + (size_t)rep_dst[did] * 640;
    if (cnt_dst[did] == 1) {
        pd[c] = typ * dm; pd[128 + c] = dv * dm; pd[256 + c] = sv * dm;
        pd[384 + c] = tse * dm; pd[512 + c] = ev * dm;
    } else {
        atomicAdd(pd + c, typ * dm);
        atomicAdd(pd + 128 + c, dv * dm);
        atomicAdd(pd + 256 + c, sv * dm);
        atomicAdd(pd + 384 + c, tse * dm);
        atomicAdd(pd + 512 + c, ev * dm);
    }
}

// ---- gather aggregated means back per event into Xg (8192 x 640) ----
__global__ void k_build_xg(const int* __restrict__ src_ids, const int* __restrict__ dst_ids,
                           const unsigned* __restrict__ rep_src, const unsigned* __restrict__ rep_dst,
                           const int* __restrict__ cnt_src, const int* __restrict__ cnt_dst,
                           const float* __restrict__ sum_src, const float* __restrict__ sum_dst,
                           float* __restrict__ Xg) {
    int r = blockIdx.x;
    int c = blockIdx.y * 128 + threadIdx.x;  // gridDim.y = 5
    float v;
    if (r < EVT) {
        int id = src_ids[r];
        int cnt = cnt_src[id]; if (cnt < 1) cnt = 1;
        v = sum_src[(size_t)rep_src[id] * 640 + c] / (float)cnt;
    } else {
        int id = dst_ids[r - EVT];
        int cnt = cnt_dst[id]; if (cnt < 1) cnt = 1;
        v = sum_dst[(size_t)rep_dst[id] * 640 + c] / (float)cnt;
    }
    Xg[(size_t)r * 640 + c] = v;
}

__global__ void k_build_hg(const int* __restrict__ src_ids, const int* __restrict__ dst_ids,
                           const float* __restrict__ memory, float* __restrict__ Hg) {
    int r = blockIdx.x, c = threadIdx.x;
    int id = (r < EVT) ? src_ids[r] : dst_ids[r - EVT];
    Hg[(size_t)r * HID + c] = memory[(size_t)id * HID + c];
}

// ---- generic fp32 tiled GEMM: C[M,N] (+)= A[M,K] @ W[N,K]^T (+ bias) ----
__global__ __launch_bounds__(256) void k_gemm(const float* __restrict__ A,
                                              const float* __restrict__ W,
                                              const float* __restrict__ bias,
                                              float* __restrict__ C,
                                              int M, int N, int K, int acc) {
    __shared__ float As[16][68];
    __shared__ float Ws[16][132];
    int tid = threadIdx.x;
    int bm = blockIdx.x * 64;
    int bn = blockIdx.y * 128;
    int tx = tid & 15, ty = tid >> 4;
    float accr[4][8];
#pragma unroll
    for (int i = 0; i < 4; i++)
#pragma unroll
        for (int j = 0; j < 8; j++) accr[i][j] = 0.f;
    int ar = tid >> 2, ak = (tid & 3) * 4;
    int wr = tid >> 1, wk = (tid & 1) * 8;
    for (int k0 = 0; k0 < K; k0 += 16) {
        float4 av = make_float4(0.f, 0.f, 0.f, 0.f);
        int arow = bm + ar;
        if (arow < M) av = *(const float4*)(A + (size_t)arow * K + k0 + ak);
        As[ak + 0][ar] = av.x; As[ak + 1][ar] = av.y; As[ak + 2][ar] = av.z; As[ak + 3][ar] = av.w;
        int wrow = bn + wr;
        float4 w0 = *(const float4*)(W + (size_t)wrow * K + k0 + wk);
        float4 w1 = *(const float4*)(W + (size_t)wrow * K + k0 + wk + 4);
        Ws[wk + 0][wr] = w0.x; Ws[wk + 1][wr] = w0.y; Ws[wk + 2][wr] = w0.z; Ws[wk + 3][wr] = w0.w;
        Ws[wk + 4][wr] = w1.x; Ws[wk + 5][wr] = w1.y; Ws[wk + 6][wr] = w1.z; Ws[wk + 7][wr] = w1.w;
        __syncthreads();
#pragma unroll
        for (int kk = 0; kk < 16; ++kk) {
            float a[4], b[8];
#pragma unroll
            for (int i = 0; i < 4; i++) a[i] = As[kk][ty * 4 + i];
#pragma unroll
            for (int j = 0; j < 8; j++) b[j] = Ws[kk][tx * 8 + j];
#pragma unroll
            for (int i = 0; i < 4; i++)
#pragma unroll
                for (int j = 0; j < 8; j++) accr[i][j] += a[i] * b[j];
        }
        __syncthreads();
    }
#pragma unroll
    for (int i = 0; i < 4; i++) {
        int row = bm + ty * 4 + i;
        if (row >= M) continue;
#pragma unroll
        for (int j = 0; j < 8; j++) {
            int col = bn + tx * 8 + j;
            float v = accr[i][j];
            if (bias) v += bias[col];
            if (acc) v += C[(size_t)row * N + col];
            C[(size_t)row * N + col] = v;
        }
    }
}

// ---- GRU gate combine ----
__global__ void k_gru(const float* __restrict__ Gi, const float* __restrict__ Gh,
                      const float* __restrict__ Hg, float* __restrict__ newmem) {
    int r = blockIdx.x, c = threadIdx.x;
    const float* gi = Gi + (size_t)r * 384;
    const float* gh = Gh + (size_t)r * 384;
    float rg = sigmoidf_(gi[c] + gh[c]);
    float z  = sigmoidf_(gi[128 + c] + gh[128 + c]);
    float n  = tanhf(gi[256 + c] + rg * gh[256 + c]);
    float h  = Hg[(size_t)r * HID + c];
    newmem[(size_t)r * HID + c] = (1.f - z) * n + z * h;
}

__global__ void k_scatter(float* __restrict__ memory, const int* __restrict__ ids,
                          const float* __restrict__ newmem) {
    int i = blockIdx.x, c = threadIdx.x;
    memory[(size_t)ids[i] * HID + c] = newmem[(size_t)i * HID + c];
}

// ---- fused node-GEMM weight: rows q|k|v|skip|qe ----
__global__ void k_wall(const float* __restrict__ wq, const float* __restrict__ wk_,
                       const float* __restrict__ wv, const float* __restrict__ wskip,
                       const float* __restrict__ we, const float* __restrict__ bq,
                       const float* __restrict__ bk, const float* __restrict__ bv,
                       const float* __restrict__ bskip, float* __restrict__ Wall,
                       float* __restrict__ ball) {
    int row = blockIdx.x;
    int k = threadIdx.x;
    float v;
    if (row < 128)      v = wq[row * 128 + k];
    else if (row < 256) v = wk_[(row - 128) * 128 + k];
    else if (row < 384) v = wv[(row - 256) * 128 + k];
    else if (row < 512) v = wskip[(row - 384) * 128 + k];
    else {
        int j = row - 512;
        float a = 0.f;
        for (int t = 0; t < 128; t++) a += wq[t * 128 + k] * we[t * 256 + j];
        v = a;
    }
    Wall[row * 128 + k] = v;
    if (k == 0) {
        float b;
        if (row < 128)      b = bq[row];
        else if (row < 256) b = bk[row - 128];
        else if (row < 384) b = bv[row - 256];
        else if (row < 512) b = bskip[row - 384];
        else { int j = row - 512; float a = 0.f; for (int t = 0; t < 128; t++) a += bq[t] * we[t * 256 + j]; b = a; }
        ball[row] = b;
    }
}

__global__ void k_x(const int* __restrict__ node_ids, const float* __restrict__ nf,
                    const float* __restrict__ memory, float* __restrict__ X) {
    int p = blockIdx.x, c = threadIdx.x;
    int nid = node_ids[p];
    X[(size_t)p * HID + c] = nf[(size_t)nid * HID + c] + memory[(size_t)nid * HID + c];
}

// ---- dst-degree histogram ----
__global__ void k_deg(const int* __restrict__ eidx, int* __restrict__ deg) {
    int j = blockIdx.x * blockDim.x + threadIdx.x;
    if (j >= NEDGE) return;
    atomicAdd(&deg[eidx[NEDGE + j]], 1);
}

// ---- exclusive prefix sum over 20000 degrees (single block) ----
__global__ __launch_bounds__(1024) void k_scan(const int* __restrict__ deg,
                                               int* __restrict__ offs, int* __restrict__ cursor) {
    __shared__ int part[1024];
    int t = threadIdx.x;
    int base = t * 20;
    int loc[20]; int s = 0;
    for (int i = 0; i < 20; i++) { int idx = base + i; int v = (idx < NNODE) ? deg[idx] : 0; loc[i] = s; s += v; }
    part[t] = s; __syncthreads();
    for (int dgap = 1; dgap < 1024; dgap <<= 1) {
        int v = (t >= dgap) ? part[t - dgap] : 0;
        __syncthreads();
        part[t] += v;
        __syncthreads();
    }
    int excl = (t == 0) ? 0 : part[t - 1];
    for (int i = 0; i < 20; i++) { int idx = base + i; if (idx < NNODE) { int o = excl + loc[i]; offs[idx] = o; cursor[idx] = o; } }
    if (t == 1023) offs[NNODE] = part[1023];
}

__global__ void k_sortscat(const int* __restrict__ eidx, int* __restrict__ cursor,
                           int* __restrict__ sorted) {
    int j = blockIdx.x * blockDim.x + threadIdx.x;
    if (j >= NEDGE) return;
    int d = eidx[NEDGE + j];
    int pos = atomicAdd(&cursor[d], 1);
    sorted[pos] = j;
}

// ---- fused per-node attention: alpha + online softmax + accumulate ----
// One wave per node; lane handles channels 2*lane, 2*lane+1.
__global__ __launch_bounds__(256) void k_node(const float* __restrict__ QK,
        const int* __restrict__ offs, const int* __restrict__ sorted,
        const int* __restrict__ eidx, const int* __restrict__ edge_ids,
        const float* __restrict__ last_update, const float* __restrict__ time_w,
        const float* __restrict__ time_b, const float* __restrict__ ef,
        const int* __restrict__ tptr, float* __restrict__ out, float* __restrict__ sacc) {
    int wave = threadIdx.x >> 6, lane = threadIdx.x & 63;
    int n = blockIdx.x * 4 + wave;
    int c = 2 * lane;
    const float* base = QK + (size_t)n * 768;
    float2 qd   = *(const float2*)(base + c);
    float2 skip = *(const float2*)(base + 384 + c);
    float2 qet  = *(const float2*)(base + 512 + c);
    float2 qef  = *(const float2*)(base + 640 + c);
    float2 tw   = *(const float2*)(time_w + c);
    float2 tb   = *(const float2*)(time_b + c);
    float tf = (float)(*tptr);
    int start = offs[n], end = offs[n + 1];
    float m = -1e30f, l_ = 0.f;
    float va0 = 0.f, va1 = 0.f, s00 = 0.f, s01 = 0.f, s10 = 0.f, s11 = 0.f;
    for (int cb = start; cb < end; cb += 64) {
        int cnt = end - cb; if (cnt > 64) cnt = 64;
        // prefetch per-edge scalars into lanes
        int s_l = 0, eid_l = 0; float rt_l = 0.f;
        if (lane < cnt) {
            int j = sorted[cb + lane];
            s_l = eidx[j];
            eid_l = edge_ids[j];
            rt_l = tf - last_update[eid_l];
        }
        for (int e = 0; e < cnt; ++e) {
            int s   = __shfl(s_l, e, 64);
            int eid = __shfl(eid_l, e, 64);
            float rt = __shfl(rt_l, e, 64);
            const float* sb = QK + (size_t)s * 768;
            float2 kv = *(const float2*)(sb + 128 + c);
            float2 vv = *(const float2*)(sb + 256 + c);
            float2 ev = *(const float2*)(ef + (size_t)eid * HID + c);
            float cv0 = __cosf(rt * tw.x + tb.x);
            float cv1 = __cosf(rt * tw.y + tb.y);
            float p = qd.x * kv.x + qd.y * kv.y + qet.x * cv0 + qet.y * cv1
                    + qef.x * ev.x + qef.y * ev.y;
#pragma unroll
            for (int msk = 32; msk > 0; msk >>= 1) p += __shfl_xor(p, msk, 64);
            float alpha = p * 0.08838834764831845f;     // 1/sqrt(128)
            if (alpha > m) {
                float fac = __expf(m - alpha);
                l_ *= fac; va0 *= fac; va1 *= fac;
                s00 *= fac; s01 *= fac; s10 *= fac; s11 *= fac;
                m = alpha;
            }
            float w = __expf(alpha - m);
            l_ += w;
            va0 += w * vv.x; va1 += w * vv.y;
            s00 += w * cv0;  s01 += w * cv1;
            s10 += w * ev.x; s11 += w * ev.y;
        }
    }
    float inv = 1.f / fmaxf(l_, 1e-16f);
    float2 o; o.x = va0 * inv + skip.x; o.y = va1 * inv + skip.y;
    *(float2*)(out + (size_t)n * HID + c) = o;
    float2 t0; t0.x = s00 * inv; t0.y = s01 * inv;
    float2 t1; t1.x = s10 * inv; t1.y = s11 * inv;
    *(float2*)(sacc + (size_t)n * 256 + c) = t0;
    *(float2*)(sacc + (size_t)n * 256 + 128 + c) = t1;
}

extern "C" void kernel_launch(void* const* d_in, const int* in_sizes, int n_in,
                              void* d_out, int out_size, void* d_ws, size_t ws_size,
                              hipStream_t stream) {
    const int*   et_ids        = (const int*)d_in[0];
    const int*   src_ids       = (const int*)d_in[1];
    const float* src_mask      = (const float*)d_in[2];
    const int*   dst_ids       = (const int*)d_in[3];
    const float* dst_mask      = (const float*)d_in[4];
    const int*   ev_eids       = (const int*)d_in[5];
    const float* ev_emb        = (const float*)d_in[6];
    const float* ev_mask       = (const float*)d_in[7];
    const float* ev_ts         = (const float*)d_in[8];
    const int*   node_ids      = (const int*)d_in[9];
    const int*   edge_ids      = (const int*)d_in[10];
    const int*   edge_index    = (const int*)d_in[11];
    const int*   tptr          = (const int*)d_in[12];
    float*       memory        = (float*)d_in[13];
    const float* last_update   = (const float*)d_in[14];
    const float* node_features = (const float*)d_in[15];
    const float* edge_features = (const float*)d_in[16];
    const float* time_w        = (const float*)d_in[17];
    const float* time_b        = (const float*)d_in[18];
    const float* w_ih          = (const float*)d_in[19];
    const float* w_hh          = (const float*)d_in[20];
    const float* b_ih          = (const float*)d_in[21];
    const float* b_hh          = (const float*)d_in[22];
    const float* wq            = (const float*)d_in[23];
    const float* bq            = (const float*)d_in[24];
    const float* wk            = (const float*)d_in[25];
    const float* bk            = (const float*)d_in[26];
    const float* wv            = (const float*)d_in[27];
    const float* bv            = (const float*)d_in[28];
    const float* we            = (const float*)d_in[29];
    const float* wskip         = (const float*)d_in[30];
    const float* bskip         = (const float*)d_in[31];
    float* out = (float*)d_out;
    char*  wsb = (char*)d_ws;

    unsigned* rep_src = (unsigned*)(wsb + OFF_REP_SRC);
    unsigned* rep_dst = (unsigned*)(wsb + OFF_REP_DST);
    int*   cnt_src = (int*)(wsb + OFF_CNT_SRC);
    int*   cnt_dst = (int*)(wsb + OFF_CNT_DST);
    float* sum_src = (float*)(wsb + OFF_SUM_SRC);
    float* sum_dst = (float*)(wsb + OFF_SUM_DST);
    float* Xg      = (float*)(wsb + OFF_XG);
    float* Hg      = (float*)(wsb + OFF_HG);
    float* Gi      = (float*)(wsb + OFF_GI);
    float* Gh      = (float*)(wsb + OFF_GH);
    float* newmem  = (float*)(wsb + OFF_NEWMEM);
    float* X       = (float*)(wsb + OFF_X);
    float* QKVSE   = (float*)(wsb + OFF_QKVSE);
    float* Wall    = (float*)(wsb + OFF_WALL);
    float* ball    = (float*)(wsb + OFF_BALL);
    int*   deg     = (int*)(wsb + OFF_DEG);
    int*   offs    = (int*)(wsb + OFF_OFFS);
    int*   cursor  = (int*)(wsb + OFF_CURSOR);
    int*   sorted  = (int*)(wsb + OFF_SORTED);
    float* sacc    = (float*)(wsb + OFF_SACC);

    // ---- event phase ----
    hipMemsetAsync(wsb + OFF_REP_SRC, 0xFF, 800256, stream);
    hipMemsetAsync(wsb + OFF_CNT_SRC, 0, 800256, stream);
    hipMemsetAsync(wsb + OFF_SUM_SRC, 0, 2u * 10485760u, stream);
    k_tables<<<16, 256, 0, stream>>>(src_ids, dst_ids, rep_src, rep_dst, cnt_src, cnt_dst);
    k_message<<<EVT, 128, 0, stream>>>(et_ids, src_ids, src_mask, dst_ids, dst_mask, ev_eids,
                                       ev_emb, ev_mask, ev_ts, memory, last_update, time_w, time_b,
                                       rep_src, rep_dst, cnt_src, cnt_dst, sum_src, sum_dst);
    k_build_xg<<<dim3(2 * EVT, 5), 128, 0, stream>>>(src_ids, dst_ids, rep_src, rep_dst,
                                                     cnt_src, cnt_dst, sum_src, sum_dst, Xg);
    k_build_hg<<<2 * EVT, 128, 0, stream>>>(src_ids, dst_ids, memory, Hg);
    k_gemm<<<dim3(128, 3), 256, 0, stream>>>(Xg, w_ih, b_ih, Gi, 2 * EVT, 384, 640, 0);
    k_gemm<<<dim3(128, 3), 256, 0, stream>>>(Hg, w_hh, b_hh, Gh, 2 * EVT, 384, 128, 0);
    k_gru<<<2 * EVT, 128, 0, stream>>>(Gi, Gh, Hg, newmem);
    k_scatter<<<EVT, 128, 0, stream>>>(memory, src_ids, newmem);
    k_scatter<<<EVT, 128, 0, stream>>>(memory, dst_ids, newmem + (size_t)EVT * HID);

    // ---- node phase ----
    k_wall<<<768, 128, 0, stream>>>(wq, wk, wv, wskip, we, bq, bk, bv, bskip, Wall, ball);
    k_x<<<NNODE, 128, 0, stream>>>(node_ids, node_features, memory, X);
    k_gemm<<<dim3(313, 6), 256, 0, stream>>>(X, Wall, ball, QKVSE, NNODE, 768, 128, 0);
    hipMemsetAsync(wsb + OFF_DEG, 0, 80128, stream);
    k_deg<<<1250, 256, 0, stream>>>(edge_index, deg);
    k_scan<<<1, 1024, 0, stream>>>(deg, offs, cursor);
    k_sortscat<<<1250, 256, 0, stream>>>(edge_index, cursor, sorted);
    k_node<<<NNODE / 4, 256, 0, stream>>>(QKVSE, offs, sorted, edge_index, edge_ids,
                                          last_update, time_w, time_b, edge_features, tptr,
                                          out, sacc);
    k_gemm<<<dim3(313, 1), 256, 0, stream>>>(sacc, we, nullptr, out, NNODE, 128, 256, 1);
}

// Round 3
// 559.390 us; speedup vs baseline: 1.4481x; 1.2938x over previous
//
#include <hip/hip_runtime.h>
#include <math.h>

#define HID   128
#define MAXN  100000
#define MAXE  300000
#define EVT   4096
#define NNODE 20000
#define NEDGE 320000

typedef unsigned short u16;
typedef __attribute__((ext_vector_type(8))) short bf16x8;
typedef __attribute__((ext_vector_type(4))) float f32x4;

// ---------------- workspace layout (bytes) ----------------
// PERSIST (weights, live for whole launch)
#define OFF_WIHB      0u            // 384*640 bf16
#define OFF_WHHB      491520u      // 384*128 bf16
#define OFF_WEB       589824u      // 128*256 bf16
#define OFF_WALLB     655360u      // 768*128 bf16
#define OFF_BALL      851968u      // 768 f32
#define BASE2         855040u
// EVENT arena (from BASE2)
#define OFF_REP_SRC   (BASE2 + 0u)
#define OFF_REP_DST   (BASE2 + 400128u)
#define OFF_CNT_SRC   (BASE2 + 800256u)
#define OFF_CNT_DST   (BASE2 + 1200384u)
#define OFF_SUM_SRC   (BASE2 + 1600512u)    // 4096*640 f32
#define OFF_SUM_DST   (BASE2 + 12086272u)   // 4096*640 f32
#define OFF_XGB       (BASE2 + 22572032u)   // 8192*640 bf16
#define OFF_HG        (BASE2 + 33057792u)   // 8192*128 f32
#define OFF_HGB       (BASE2 + 37252096u)   // 8192*128 bf16
#define OFF_GI        (BASE2 + 39349248u)   // 8192*384 f32
#define OFF_GH        (BASE2 + 51932160u)   // 8192*384 f32
#define OFF_NEWMEM    (BASE2 + 64515072u)   // 8192*128 f32
// NODE arena (aliases EVENT arena; event phase fully complete first)
#define OFF_XB        (BASE2 + 0u)          // 20000*128 bf16
#define OFF_QKVSE     (BASE2 + 5120000u)    // 20000*768 f32
#define OFF_KVB       (BASE2 + 66560000u)   // 20000*256 bf16
#define OFF_DEG       (BASE2 + 76800000u)   // 20000 i32
#define OFF_OFFS      (BASE2 + 76880128u)   // 20001 i32
#define OFF_CURSOR    (BASE2 + 76960256u)   // 20000 i32
#define OFF_BSUM      (BASE2 + 77040384u)   // 256 i32
#define OFF_SORTED    (BASE2 + 77041664u)   // 320000 i32
#define OFF_SACCB     (BASE2 + 78321664u)   // 20000*256 bf16
// peak ~89.4 MB

__device__ __forceinline__ float sigmoidf_(float x) { return 1.f / (1.f + __expf(-x)); }
__device__ __forceinline__ u16 f2b(float f) {
    unsigned u = __float_as_uint(f);
    unsigned r = (u + 0x7fffu + ((u >> 16) & 1u)) >> 16;
    return (u16)r;
}
__device__ __forceinline__ float b2f(unsigned h) { return __uint_as_float(h << 16); }

// ---- fp32 -> bf16 convert ----
__global__ void k_cvt(const float* __restrict__ s, u16* __restrict__ d, int n) {
    int i = blockIdx.x * blockDim.x + threadIdx.x;
    if (i < n) d[i] = f2b(s[i]);
}

// ---- rep/count tables for scatter-mean ----
__global__ void k_tables(const int* __restrict__ src_ids, const int* __restrict__ dst_ids,
                         unsigned* rep_src, unsigned* rep_dst, int* cnt_src, int* cnt_dst) {
    int i = blockIdx.x * blockDim.x + threadIdx.x;
    if (i >= EVT) return;
    int s = src_ids[i], d = dst_ids[i];
    atomicMin(&rep_src[s], (unsigned)i);
    atomicAdd(&cnt_src[s], 1);
    atomicMin(&rep_dst[d], (unsigned)i);
    atomicAdd(&cnt_dst[d], 1);
}

// ---- build messages and aggregate into per-rep sums (fast path when unique) ----
__global__ void k_message(const int* __restrict__ et_ids, const int* __restrict__ src_ids,
                          const float* __restrict__ src_mask, const int* __restrict__ dst_ids,
                          const float* __restrict__ dst_mask, const int* __restrict__ ev_eids,
                          const float* __restrict__ ev_emb, const float* __restrict__ ev_mask,
                          const float* __restrict__ ev_ts, const float* __restrict__ memory,
                          const float* __restrict__ last_update, const float* __restrict__ time_w,
                          const float* __restrict__ time_b, const unsigned* __restrict__ rep_src,
                          const unsigned* __restrict__ rep_dst, const int* __restrict__ cnt_src,
                          const int* __restrict__ cnt_dst, float* sum_src, float* sum_dst) {
    int i = blockIdx.x;
    int c = threadIdx.x;
    int et = et_ids[i];
    float sm = src_mask[i], dm = dst_mask[i], em = ev_mask[i], ts = ev_ts[i];
    int sid = src_ids[i], did = dst_ids[i], eid = ev_eids[i];
    float isnode = (et == 3 || et == 4) ? 1.f : 0.f;
    float rel = ts - last_update[eid] * dm;
    float tval = ts * isnode + rel * dm;
    float tse = __cosf(tval * time_w[c] + time_b[c]) * em;
    float typ = (float)et;
    float sv = memory[(size_t)sid * HID + c] * sm;
    float dv = memory[(size_t)did * HID + c] * dm;
    float ev = ev_emb[(size_t)i * HID + c];
    float* ps = sum_src + (size_t)rep_src[sid] * 640;
    if (cnt_src[sid] == 1) {
        ps[c] = typ * em; ps[128 + c] = sv * em; ps[256 + c] = dv * em;
        ps[384 + c] = tse * em; ps[512 + c] = ev * em;
    } else {
        atomicAdd(ps + c, typ * em);
        atomicAdd(ps + 128 + c, sv * em);
        atomicAdd(ps + 256 + c, dv * em);
        atomicAdd(ps + 384 + c, tse * em);
        atomicAdd(ps + 512 + c, ev * em);
    }
    float* pd = sum_dst + (size_t)rep_dst[did] * 640;
    if (cnt_dst[did] == 1) {
        pd[c] = typ * dm; pd[128 + c] = dv * dm; pd[256 + c] = sv * dm;
        pd[384 + c] = tse * dm; pd[512 + c] = ev * dm;
    } else {
        atomicAdd(pd + c, typ * dm);
        atomicAdd(pd + 128 + c, dv * dm);
        atomicAdd(pd + 256 + c, sv * dm);
        atomicAdd(pd + 384 + c, tse * dm);
        atomicAdd(pd + 512 + c, ev * dm);
    }
}

// ---- gather aggregated means per event into Xg_b (8192 x 640 bf16) ----
__global__ void k_build_xg(const int* __restrict__ src_ids, const int* __restrict__ dst_ids,
                           const unsigned* __restrict__ rep_src, const unsigned* __restrict__ rep_dst,
                           const int* __restrict__ cnt_src, const int* __restrict__ cnt_dst,
                           const float* __restrict__ sum_src, const float* __restrict__ sum_dst,
                           u16* __restrict__ Xgb) {
    int r = blockIdx.x;
    int c = blockIdx.y * 128 + threadIdx.x;  // gridDim.y = 5
    float v;
    if (r < EVT) {
        int id = src_ids[r];
        int cnt = cnt_src[id]; if (cnt < 1) cnt = 1;
        v = sum_src[(size_t)rep_src[id] * 640 + c] / (float)cnt;
    } else {
        int id = dst_ids[r - EVT];
        int cnt = cnt_dst[id]; if (cnt < 1) cnt = 1;
        v = sum_dst[(size_t)rep_dst[id] * 640 + c] / (float)cnt;
    }
    Xgb[(size_t)r * 640 + c] = f2b(v);
}

__global__ void k_build_hg(const int* __restrict__ src_ids, const int* __restrict__ dst_ids,
                           const float* __restrict__ memory, float* __restrict__ Hg,
                           u16* __restrict__ Hgb) {
    int r = blockIdx.x, c = threadIdx.x;
    int id = (r < EVT) ? src_ids[r] : dst_ids[r - EVT];
    float v = memory[(size_t)id * HID + c];
    Hg[(size_t)r * HID + c] = v;
    Hgb[(size_t)r * HID + c] = f2b(v);
}

// ---- MFMA bf16 GEMM: C[M,N] (+)= A[M,K] @ W[N,K]^T (+bias); opt. bf16 side-write of cols 128..384 ----
// 128x128 tile, 256 threads (4 waves, each 64x64), BK=32, mfma_f32_16x16x32_bf16.
__global__ __launch_bounds__(256) void k_gemm_mfma(const u16* __restrict__ A,
                                                   const u16* __restrict__ W,
                                                   const float* __restrict__ bias,
                                                   float* __restrict__ C,
                                                   u16* __restrict__ KVb,
                                                   int M, int N, int K, int acc) {
    __shared__ u16 Als[128 * 40];
    __shared__ u16 Wls[128 * 40];
    int tid = threadIdx.x;
    int bm = blockIdx.x * 128, bn = blockIdx.y * 128;
    int wave = tid >> 6, lane = tid & 63;
    int wm = (wave & 1) * 64, wn = (wave >> 1) * 64;
    int l15 = lane & 15, quad = lane >> 4;
    f32x4 accf[4][4] = {};
    for (int k0 = 0; k0 < K; k0 += 32) {
#pragma unroll
        for (int h = 0; h < 2; ++h) {
            int ch = tid + h * 256;
            int row = ch >> 2, kc = (ch & 3) * 8;
            int gr = bm + row;
            float4 av = make_float4(0.f, 0.f, 0.f, 0.f);
            if (gr < M) av = *(const float4*)(A + (size_t)gr * K + k0 + kc);
            *(float4*)&Als[row * 40 + kc] = av;
            int wr = bn + row;
            float4 wv_ = *(const float4*)(W + (size_t)wr * K + k0 + kc);
            *(float4*)&Wls[row * 40 + kc] = wv_;
        }
        __syncthreads();
        bf16x8 af[4], bfr[4];
#pragma unroll
        for (int r = 0; r < 4; ++r)
            af[r] = *(const bf16x8*)&Als[(wm + r * 16 + l15) * 40 + quad * 8];
#pragma unroll
        for (int c2 = 0; c2 < 4; ++c2)
            bfr[c2] = *(const bf16x8*)&Wls[(wn + c2 * 16 + l15) * 40 + quad * 8];
#pragma unroll
        for (int r = 0; r < 4; ++r)
#pragma unroll
            for (int c2 = 0; c2 < 4; ++c2)
                accf[r][c2] = __builtin_amdgcn_mfma_f32_16x16x32_bf16(af[r], bfr[c2], accf[r][c2], 0, 0, 0);
        __syncthreads();
    }
#pragma unroll
    for (int r = 0; r < 4; ++r) {
#pragma unroll
        for (int c2 = 0; c2 < 4; ++c2) {
            int ncol = bn + wn + c2 * 16 + l15;
            float bv = bias ? bias[ncol] : 0.f;
#pragma unroll
            for (int reg = 0; reg < 4; ++reg) {
                int mrow = bm + wm + r * 16 + quad * 4 + reg;
                if (mrow >= M) continue;
                float v = accf[r][c2][reg] + bv;
                if (acc) v += C[(size_t)mrow * N + ncol];
                C[(size_t)mrow * N + ncol] = v;
                if (KVb && ncol >= 128 && ncol < 384)
                    KVb[(size_t)mrow * 256 + (ncol - 128)] = f2b(v);
            }
        }
    }
}

// ---- GRU gate combine ----
__global__ void k_gru(const float* __restrict__ Gi, const float* __restrict__ Gh,
                      const float* __restrict__ Hg, float* __restrict__ newmem) {
    int r = blockIdx.x, c = threadIdx.x;
    const float* gi = Gi + (size_t)r * 384;
    const float* gh = Gh + (size_t)r * 384;
    float rg = sigmoidf_(gi[c] + gh[c]);
    float z  = sigmoidf_(gi[128 + c] + gh[128 + c]);
    float n  = tanhf(gi[256 + c] + rg * gh[256 + c]);
    float h  = Hg[(size_t)r * HID + c];
    newmem[(size_t)r * HID + c] = (1.f - z) * n + z * h;
}

__global__ void k_scatter(float* __restrict__ memory, const int* __restrict__ ids,
                          const float* __restrict__ newmem) {
    int i = blockIdx.x, c = threadIdx.x;
    memory[(size_t)ids[i] * HID + c] = newmem[(size_t)i * HID + c];
}

// ---- fused node-GEMM weight (bf16): rows q|k|v|skip|qe ----
__global__ void k_wall(const float* __restrict__ wq, const float* __restrict__ wk_,
                       const float* __restrict__ wv, const float* __restrict__ wskip,
                       const float* __restrict__ we, const float* __restrict__ bq,
                       const float* __restrict__ bk, const float* __restrict__ bv,
                       const float* __restrict__ bskip, u16* __restrict__ Wallb,
                       float* __restrict__ ball) {
    int row = blockIdx.x;
    int k = threadIdx.x;
    float v;
    if (row < 128)      v = wq[row * 128 + k];
    else if (row < 256) v = wk_[(row - 128) * 128 + k];
    else if (row < 384) v = wv[(row - 256) * 128 + k];
    else if (row < 512) v = wskip[(row - 384) * 128 + k];
    else {
        int j = row - 512;
        float a = 0.f;
        for (int t = 0; t < 128; t++) a += wq[t * 128 + k] * we[t * 256 + j];
        v = a;
    }
    Wallb[row * 128 + k] = f2b(v);
    if (k == 0) {
        float b;
        if (row < 128)      b = bq[row];
        else if (row < 256) b = bk[row - 128];
        else if (row < 384) b = bv[row - 256];
        else if (row < 512) b = bskip[row - 384];
        else { int j = row - 512; float a = 0.f; for (int t = 0; t < 128; t++) a += bq[t] * we[t * 256 + j]; b = a; }
        ball[row] = b;
    }
}

__global__ void k_x(const int* __restrict__ node_ids, const float* __restrict__ nf,
                    const float* __restrict__ memory, u16* __restrict__ Xb) {
    int p = blockIdx.x, c = threadIdx.x;
    int nid = node_ids[p];
    Xb[(size_t)p * HID + c] = f2b(nf[(size_t)nid * HID + c] + memory[(size_t)nid * HID + c]);
}

// ---- dst-degree histogram ----
__global__ void k_deg(const int* __restrict__ eidx, int* __restrict__ deg) {
    int j = blockIdx.x * blockDim.x + threadIdx.x;
    if (j >= NEDGE) return;
    atomicAdd(&deg[eidx[NEDGE + j]], 1);
}

// ---- multi-block exclusive scan over 20000 degrees ----
__global__ __launch_bounds__(256) void k_scan1(const int* __restrict__ deg,
                                               int* __restrict__ offs, int* __restrict__ bsum) {
    __shared__ int wsum[4];
    int i = blockIdx.x * 256 + threadIdx.x;
    int v = (i < NNODE) ? deg[i] : 0;
    int lane = threadIdx.x & 63, w = threadIdx.x >> 6;
    int x = v;
#pragma unroll
    for (int d = 1; d < 64; d <<= 1) { int y = __shfl_up(x, d, 64); if (lane >= d) x += y; }
    if (lane == 63) wsum[w] = x;
    __syncthreads();
    int add = 0;
    for (int k = 0; k < w; ++k) add += wsum[k];
    int incl = x + add;
    if (i < NNODE) offs[i] = incl - v;          // local exclusive
    if (threadIdx.x == 255) bsum[blockIdx.x] = incl;
}

__global__ __launch_bounds__(128) void k_scan2(int* __restrict__ bsum, int nb) {
    __shared__ int w0s;
    int t = threadIdx.x;
    int v = (t < nb) ? bsum[t] : 0;
    int lane = t & 63, w = t >> 6;
    int x = v;
#pragma unroll
    for (int d = 1; d < 64; d <<= 1) { int y = __shfl_up(x, d, 64); if (lane >= d) x += y; }
    if (t == 63) w0s = x;
    __syncthreads();
    if (w == 1) x += w0s;
    if (t < nb) bsum[t] = x - v;                // exclusive
}

__global__ __launch_bounds__(256) void k_scan3(int* __restrict__ offs, const int* __restrict__ bsum,
                                               int* __restrict__ cursor) {
    int i = blockIdx.x * 256 + threadIdx.x;
    if (i < NNODE) { int o = offs[i] + bsum[blockIdx.x]; offs[i] = o; cursor[i] = o; }
    if (i == 0) offs[NNODE] = NEDGE;
}

__global__ void k_sortscat(const int* __restrict__ eidx, int* __restrict__ cursor,
                           int* __restrict__ sorted) {
    int j = blockIdx.x * blockDim.x + threadIdx.x;
    if (j >= NEDGE) return;
    int d = eidx[NEDGE + j];
    int pos = atomicAdd(&cursor[d], 1);
    sorted[pos] = j;
}

// ---- fused per-node attention: 4-edge batched online softmax ----
__global__ __launch_bounds__(256) void k_node(const float* __restrict__ QK,
        const u16* __restrict__ KVb, const int* __restrict__ offs,
        const int* __restrict__ sorted, const int* __restrict__ eidx,
        const int* __restrict__ edge_ids, const float* __restrict__ last_update,
        const float* __restrict__ time_w, const float* __restrict__ time_b,
        const float* __restrict__ ef, const int* __restrict__ tptr,
        float* __restrict__ out, u16* __restrict__ saccb) {
    int wave = threadIdx.x >> 6, lane = threadIdx.x & 63;
    int n = blockIdx.x * 4 + wave;
    int c = 2 * lane;
    const float* base = QK + (size_t)n * 768;
    float2 qd   = *(const float2*)(base + c);
    float2 skip = *(const float2*)(base + 384 + c);
    float2 qet  = *(const float2*)(base + 512 + c);
    float2 qef  = *(const float2*)(base + 640 + c);
    float2 tw   = *(const float2*)(time_w + c);
    float2 tb   = *(const float2*)(time_b + c);
    float tf = (float)(*tptr);
    int start = offs[n], end = offs[n + 1];
    int deg = end - start;
    if (deg == 0) {
        *(float2*)(out + (size_t)n * HID + c) = skip;
        *(unsigned*)(saccb + (size_t)n * 256 + c) = 0u;
        *(unsigned*)(saccb + (size_t)n * 256 + 128 + c) = 0u;
        return;
    }
    float m = -1e30f, l_ = 0.f;
    float va0 = 0.f, va1 = 0.f, s00 = 0.f, s01 = 0.f, s10 = 0.f, s11 = 0.f;
    for (int cb = start; cb < end; cb += 64) {
        int cnt = end - cb; if (cnt > 64) cnt = 64;
        int s_l = 0, eid_l = 0; float rt_l = 0.f;
        if (lane < cnt) {
            int j = sorted[cb + lane];
            s_l = eidx[j];
            eid_l = edge_ids[j];
            rt_l = tf - last_update[eid_l];
        }
        for (int e0 = 0; e0 < cnt; e0 += 4) {
            float pv[4], cv0[4], cv1[4], vx[4], vy[4], ex[4], ey[4];
#pragma unroll
            for (int i = 0; i < 4; ++i) {
                int idx = e0 + i;
                int sel = (idx < cnt) ? idx : e0;
                int s   = __shfl(s_l, sel, 64);
                int eid = __shfl(eid_l, sel, 64);
                float rt = __shfl(rt_l, sel, 64);
                unsigned kvp = *(const unsigned*)(KVb + (size_t)s * 256 + c);
                unsigned vvp = *(const unsigned*)(KVb + (size_t)s * 256 + 128 + c);
                float2 ev = *(const float2*)(ef + (size_t)eid * HID + c);
                float k0f = b2f(kvp & 0xffffu), k1f = b2f(kvp >> 16);
                vx[i] = b2f(vvp & 0xffffu); vy[i] = b2f(vvp >> 16);
                cv0[i] = __cosf(rt * tw.x + tb.x);
                cv1[i] = __cosf(rt * tw.y + tb.y);
                ex[i] = ev.x; ey[i] = ev.y;
                pv[i] = qd.x * k0f + qd.y * k1f + qet.x * cv0[i] + qet.y * cv1[i]
                      + qef.x * ev.x + qef.y * ev.y;
            }
#pragma unroll
            for (int msk = 32; msk > 0; msk >>= 1) {
#pragma unroll
                for (int i = 0; i < 4; ++i) pv[i] += __shfl_xor(pv[i], msk, 64);
            }
            float al[4];
#pragma unroll
            for (int i = 0; i < 4; ++i)
                al[i] = (e0 + i < cnt) ? pv[i] * 0.08838834764831845f : -1e30f;
            float gm = fmaxf(fmaxf(al[0], al[1]), fmaxf(al[2], al[3]));
            if (gm > m) {
                float fac = __expf(m - gm);
                l_ *= fac; va0 *= fac; va1 *= fac;
                s00 *= fac; s01 *= fac; s10 *= fac; s11 *= fac;
                m = gm;
            }
#pragma unroll
            for (int i = 0; i < 4; ++i) {
                float w = __expf(al[i] - m);
                l_ += w;
                va0 += w * vx[i]; va1 += w * vy[i];
                s00 += w * cv0[i]; s01 += w * cv1[i];
                s10 += w * ex[i]; s11 += w * ey[i];
            }
        }
    }
    float inv = 1.f / fmaxf(l_, 1e-16f);
    float2 o; o.x = va0 * inv + skip.x; o.y = va1 * inv + skip.y;
    *(float2*)(out + (size_t)n * HID + c) = o;
    unsigned p0 = (unsigned)f2b(s00 * inv) | ((unsigned)f2b(s01 * inv) << 16);
    unsigned p1 = (unsigned)f2b(s10 * inv) | ((unsigned)f2b(s11 * inv) << 16);
    *(unsigned*)(saccb + (size_t)n * 256 + c) = p0;
    *(unsigned*)(saccb + (size_t)n * 256 + 128 + c) = p1;
}

extern "C" void kernel_launch(void* const* d_in, const int* in_sizes, int n_in,
                              void* d_out, int out_size, void* d_ws, size_t ws_size,
                              hipStream_t stream) {
    const int*   et_ids        = (const int*)d_in[0];
    const int*   src_ids       = (const int*)d_in[1];
    const float* src_mask      = (const float*)d_in[2];
    const int*   dst_ids       = (const int*)d_in[3];
    const float* dst_mask      = (const float*)d_in[4];
    const int*   ev_eids       = (const int*)d_in[5];
    const float* ev_emb        = (const float*)d_in[6];
    const float* ev_mask       = (const float*)d_in[7];
    const float* ev_ts         = (const float*)d_in[8];
    const int*   node_ids      = (const int*)d_in[9];
    const int*   edge_ids      = (const int*)d_in[10];
    const int*   edge_index    = (const int*)d_in[11];
    const int*   tptr          = (const int*)d_in[12];
    float*       memory        = (float*)d_in[13];
    const float* last_update   = (const float*)d_in[14];
    const float* node_features = (const float*)d_in[15];
    const float* edge_features = (const float*)d_in[16];
    const float* time_w        = (const float*)d_in[17];
    const float* time_b        = (const float*)d_in[18];
    const float* w_ih          = (const float*)d_in[19];
    const float* w_hh          = (const float*)d_in[20];
    const float* b_ih          = (const float*)d_in[21];
    const float* b_hh          = (const float*)d_in[22];
    const float* wq            = (const float*)d_in[23];
    const float* bq            = (const float*)d_in[24];
    const float* wk            = (const float*)d_in[25];
    const float* bk            = (const float*)d_in[26];
    const float* wv            = (const float*)d_in[27];
    const float* bv            = (const float*)d_in[28];
    const float* we            = (const float*)d_in[29];
    const float* wskip         = (const float*)d_in[30];
    const float* bskip         = (const float*)d_in[31];
    float* out = (float*)d_out;
    char*  wsb = (char*)d_ws;

    u16*   w_ih_b  = (u16*)(wsb + OFF_WIHB);
    u16*   w_hh_b  = (u16*)(wsb + OFF_WHHB);
    u16*   we_b    = (u16*)(wsb + OFF_WEB);
    u16*   Wallb   = (u16*)(wsb + OFF_WALLB);
    float* ball    = (float*)(wsb + OFF_BALL);
    unsigned* rep_src = (unsigned*)(wsb + OFF_REP_SRC);
    unsigned* rep_dst = (unsigned*)(wsb + OFF_REP_DST);
    int*   cnt_src = (int*)(wsb + OFF_CNT_SRC);
    int*   cnt_dst = (int*)(wsb + OFF_CNT_DST);
    float* sum_src = (float*)(wsb + OFF_SUM_SRC);
    float* sum_dst = (float*)(wsb + OFF_SUM_DST);
    u16*   Xgb     = (u16*)(wsb + OFF_XGB);
    float* Hg      = (float*)(wsb + OFF_HG);
    u16*   Hgb     = (u16*)(wsb + OFF_HGB);
    float* Gi      = (float*)(wsb + OFF_GI);
    float* Gh      = (float*)(wsb + OFF_GH);
    float* newmem  = (float*)(wsb + OFF_NEWMEM);
    u16*   Xb      = (u16*)(wsb + OFF_XB);
    float* QKVSE   = (float*)(wsb + OFF_QKVSE);
    u16*   KVb     = (u16*)(wsb + OFF_KVB);
    int*   deg     = (int*)(wsb + OFF_DEG);
    int*   offs    = (int*)(wsb + OFF_OFFS);
    int*   cursor  = (int*)(wsb + OFF_CURSOR);
    int*   bsum    = (int*)(wsb + OFF_BSUM);
    int*   sorted  = (int*)(wsb + OFF_SORTED);
    u16*   saccb   = (u16*)(wsb + OFF_SACCB);

    // ---- weight conversions (independent of event phase) ----
    k_cvt<<<(384 * 640 + 255) / 256, 256, 0, stream>>>(w_ih, w_ih_b, 384 * 640);
    k_cvt<<<(384 * 128 + 255) / 256, 256, 0, stream>>>(w_hh, w_hh_b, 384 * 128);
    k_cvt<<<(128 * 256 + 255) / 256, 256, 0, stream>>>(we, we_b, 128 * 256);
    k_wall<<<768, 128, 0, stream>>>(wq, wk, wv, wskip, we, bq, bk, bv, bskip, Wallb, ball);

    // ---- event phase ----
    hipMemsetAsync(wsb + OFF_REP_SRC, 0xFF, 800256, stream);
    hipMemsetAsync(wsb + OFF_CNT_SRC, 0, 800256, stream);
    hipMemsetAsync(wsb + OFF_SUM_SRC, 0, 2u * 10485760u, stream);
    k_tables<<<16, 256, 0, stream>>>(src_ids, dst_ids, rep_src, rep_dst, cnt_src, cnt_dst);
    k_message<<<EVT, 128, 0, stream>>>(et_ids, src_ids, src_mask, dst_ids, dst_mask, ev_eids,
                                       ev_emb, ev_mask, ev_ts, memory, last_update, time_w, time_b,
                                       rep_src, rep_dst, cnt_src, cnt_dst, sum_src, sum_dst);
    k_build_xg<<<dim3(2 * EVT, 5), 128, 0, stream>>>(src_ids, dst_ids, rep_src, rep_dst,
                                                     cnt_src, cnt_dst, sum_src, sum_dst, Xgb);
    k_build_hg<<<2 * EVT, 128, 0, stream>>>(src_ids, dst_ids, memory, Hg, Hgb);
    k_gemm_mfma<<<dim3(64, 3), 256, 0, stream>>>(Xgb, w_ih_b, b_ih, Gi, nullptr, 2 * EVT, 384, 640, 0);
    k_gemm_mfma<<<dim3(64, 3), 256, 0, stream>>>(Hgb, w_hh_b, b_hh, Gh, nullptr, 2 * EVT, 384, 128, 0);
    k_gru<<<2 * EVT, 128, 0, stream>>>(Gi, Gh, Hg, newmem);
    k_scatter<<<EVT, 128, 0, stream>>>(memory, src_ids, newmem);
    k_scatter<<<EVT, 128, 0, stream>>>(memory, dst_ids, newmem + (size_t)EVT * HID);

    // ---- node phase ----
    k_x<<<NNODE, 128, 0, stream>>>(node_ids, node_features, memory, Xb);
    k_gemm_mfma<<<dim3(157, 6), 256, 0, stream>>>(Xb, Wallb, ball, QKVSE, KVb, NNODE, 768, 128, 0);
    hipMemsetAsync(wsb + OFF_DEG, 0, 80128, stream);
    k_deg<<<1250, 256, 0, stream>>>(edge_index, deg);
    k_scan1<<<79, 256, 0, stream>>>(deg, offs, bsum);
    k_scan2<<<1, 128, 0, stream>>>(bsum, 79);
    k_scan3<<<79, 256, 0, stream>>>(offs, bsum, cursor);
    k_sortscat<<<1250, 256, 0, stream>>>(edge_index, cursor, sorted);
    k_node<<<NNODE / 4, 256, 0, stream>>>(QKVSE, KVb, offs, sorted, edge_index, edge_ids,
                                          last_update, time_w, time_b, edge_features, tptr,
                                          out, saccb);
    k_gemm_mfma<<<dim3(157, 1), 256, 0, stream>>>(saccb, we_b, nullptr, out, nullptr, NNODE, 128, 256, 1);
}